// Round 8
// baseline (299.345 us; speedup 1.0000x reference)
//
#include <hip/hip_runtime.h>
#include <hip/hip_fp16.h>
#include <math.h>

// Problem constants (from reference setup_inputs)
constexpr int N    = 50000;   // nodes
constexpr int E    = 800000;  // edges
constexpr int CIN  = 100;     // input channels
constexpr int CH   = 128;     // hidden channels
constexpr int COUT = 47;      // output channels
constexpr int NOUT = 25000;   // original_size (rows emitted)
constexpr int CP   = 48;      // COUT padded (storage stride)
constexpr int NB   = (N + 255) / 256;        // 196 scan blocks
constexpr int TN   = 128;                    // gemm tile nodes
constexpr int NT   = (N + TN - 1) / TN;      // 391 gemm blocks

// MFMA split-bf16 constants
constexpr int AS  = 72;   // A-stage LDS row stride (ushort) = 144 B (8 bank-starts)
constexpr int HS  = 136;  // h LDS row stride (ushort) = 272 B (16B-aligned rows)
constexpr int W1K = 256;  // w1T row length (k): [agg1 0..99|0 | w1r-x 0..99|0]
constexpr int W2K = 128;  // w2T row length (k)

// pre_kernel block partition
constexpr int HB = (E + 255) / 256;            // 3125 hist blocks
constexpr int CB = (N * CIN / 4 + 255) / 256;  // 4883 convert blocks
constexpr int PB = 193;                        // prep blocks (49280 elems)
// gather1_xw partition: xw blocks FIRST (start early, hide under gather)
constexpr int XWB = NT;                        // 391 xw gemm blocks
constexpr int GB  = N / 4;                     // 12500 gather blocks

typedef float f32x4 __attribute__((ext_vector_type(4)));
typedef short v8s  __attribute__((ext_vector_type(8)));   // 8 bf16 (4 VGPRs)

// split fp32 -> truncated bf16 hi + bf16(residual) lo.  hi+lo captures ~16
// mantissa bits; 3-term MFMA (hh+hl+lh) leaves ~2^-16 rel error per product.
__device__ __forceinline__ void bsplit(float f, ushort& h, ushort& l) {
    uint u = __float_as_uint(f);
    h = (ushort)(u >> 16);
    float fh = __uint_as_float(u & 0xffff0000u);
    l = (ushort)(__float_as_uint(f - fh) >> 16);
}

// ---------------------------------------------------------------------------
// pre_kernel: fused {hist | convert_x | prep_w} (independent work, one launch).
__global__ __launch_bounds__(256) void pre_kernel(
        const int* __restrict__ dst, int* __restrict__ cnt, int* __restrict__ rank,
        const float* __restrict__ x, __half* __restrict__ x16,
        const float* __restrict__ w1l, const float* __restrict__ w1r,
        const float* __restrict__ w2l, const float* __restrict__ w2r,
        const float* __restrict__ b2l,
        ushort* __restrict__ w1T, ushort* __restrict__ w2T,
        float* __restrict__ b2cat) {
    int bid = blockIdx.x, t = threadIdx.x;
    if (bid < HB) {
        // in-degree histogram; rank[i] = slot of edge i within its dst bucket
        int i = bid * 256 + t;
        if (i < E) rank[i] = atomicAdd(&cnt[dst[i]], 1);
    } else if (bid < HB + CB) {
        // x -> fp16 (gather payload 400B -> 200B per row)
        int i = (bid - HB) * 256 + t;
        if (i < N * CIN / 4) {
            float4 v = ((const float4*)x)[i];
            __half2 h0 = __floats2half2_rn(v.x, v.y);
            __half2 h1 = __floats2half2_rn(v.z, v.w);
            union { __half2 h[2]; uint2 u; } U;
            U.h[0] = h0; U.h[1] = h1;
            ((uint2*)x16)[i] = U.u;
        }
    } else {
        // weight transpose + bf16 hi/lo split
        // w1T: [n<128][k<256]: k<100 -> w1l[k][n]; 128<=k<228 -> w1r[k-128][n]
        // w2T: [n<128][k<128]: n<47 -> w2l[k][n]; 64<=n<111 -> w2r[k][n-64]
        int i = (bid - HB - CB) * 256 + t;
        if (i < 128 * W1K) {
            int n = i >> 8, k = i & 255;
            float v = 0.0f;
            if (k < 100)                    v = w1l[(size_t)k * CH + n];
            else if (k >= 128 && k < 228)   v = w1r[(size_t)(k - 128) * CH + n];
            ushort h, l; bsplit(v, h, l);
            w1T[i] = h; w1T[128 * W1K + i] = l;
        } else if (i < 128 * W1K + 128 * W2K) {
            int j = i - 128 * W1K;
            int n = j >> 7, k = j & 127;
            float v = 0.0f;
            if (n < COUT)                      v = w2l[(size_t)k * COUT + n];
            else if (n >= 64 && n < 64 + COUT) v = w2r[(size_t)k * COUT + (n - 64)];
            ushort h, l; bsplit(v, h, l);
            w2T[j] = h; w2T[128 * W2K + j] = l;
        } else {
            int j = i - (128 * W1K + 128 * W2K);
            if (j < 128) b2cat[j] = (j >= 64 && j < 64 + COUT) ? b2l[j - 64] : 0.0f;
        }
    }
}

// CSR stage 2a: per-block exclusive scan of cnt
__global__ __launch_bounds__(256) void scan_blocks(const int* __restrict__ cnt,
        int* __restrict__ row_ptr, int* __restrict__ blkSum) {
    __shared__ int s[256];
    int t = threadIdx.x;
    int i = blockIdx.x * 256 + t;
    int v = (i < N) ? cnt[i] : 0;
    s[t] = v;
    __syncthreads();
    for (int off = 1; off < 256; off <<= 1) {
        int a = s[t];
        int u = (t >= off) ? s[t - off] : 0;
        __syncthreads();
        s[t] = a + u;
        __syncthreads();
    }
    if (i < N) row_ptr[i] = s[t] - v;
    if (t == 255) blkSum[blockIdx.x] = s[255];
}

// CSR stage 2b: each block reduces blkSum[0..bid) itself, applies offset.
__global__ __launch_bounds__(256) void scan_apply(int* __restrict__ row_ptr,
        const int* __restrict__ blkSum) {
    __shared__ int s[256];
    int t = threadIdx.x, bid = blockIdx.x;
    int a = 0;
    for (int j = t; j < bid; j += 256) a += blkSum[j];
    s[t] = a;
    __syncthreads();
    for (int off = 128; off > 0; off >>= 1) {
        if (t < off) s[t] += s[t + off];
        __syncthreads();
    }
    int offset = s[0];
    int i = bid * 256 + t;
    if (i < N) {
        row_ptr[i] += offset;
        if (i == N - 1) row_ptr[N] = E;
    }
}

// CSR stage 3: atomic-free bucket-fill (plain stores — R16 lesson: consumers
// read col next; nt store costs ~18us e2e).
__global__ void fill_kernel(const int* __restrict__ src, const int* __restrict__ dst,
        const int* __restrict__ rank, const int* __restrict__ row_ptr,
        int* __restrict__ col) {
    int i = blockIdx.x * blockDim.x + threadIdx.x;
    if (i < E) col[row_ptr[dst[i]] + rank[i]] = src[i];
}

// ---------------------------------------------------------------------------
// R18 gather1_xw: fused {xw = x@w1r GEMM | gather1}.
// xw blocks (FIRST, 391): LDS-free split-bf16 MFMA; A-frags read straight from
// x (rows base+m, 8 cols per lane), bsplit in-register; B from w1T k=128..255
// (the w1r section). Output xw fp16 [N][128]. Runs hidden under the
// service-bound gather bulk (R14: gather time invariant to concurrency).
// gather blocks (12500): unchanged fp16 row-gather -> agg1 now stored fp16.
__global__ __launch_bounds__(256) void gather1_xw(const __half* __restrict__ x16,
        const int* __restrict__ row_ptr, const int* __restrict__ col,
        __half* __restrict__ agg1h,
        const float* __restrict__ x, const ushort* __restrict__ w1T,
        __half* __restrict__ xw) {
    int t = threadIdx.x;
    if (blockIdx.x < XWB) {
        // ---- xw GEMM block
        int base = blockIdx.x * TN;
        int lane = t & 63;
        int wv = __builtin_amdgcn_readfirstlane(t >> 6);
        int nh = wv & 1, chh = wv >> 1;
        int l15 = lane & 15, lg = lane >> 4;
        const ushort* w1Th = w1T;
        const ushort* w1Tl = w1T + 128 * W1K;
        f32x4 acc[4][4];
        #pragma unroll
        for (int mt = 0; mt < 4; ++mt)
            #pragma unroll
            for (int nt = 0; nt < 4; ++nt) acc[mt][nt] = f32x4{0.f, 0.f, 0.f, 0.f};
        #pragma unroll
        for (int ks = 0; ks < 4; ++ks) {          // K=128 (x cols >=100 are 0)
            int k0 = ks * 32 + lg * 8;
            v8s ahf[4], alf[4];
            #pragma unroll
            for (int mt = 0; mt < 4; ++mt) {
                int row = base + nh * 64 + mt * 16 + l15;
                int rr = row < N ? row : N - 1;   // clamp loads; writes guarded
                const float* xr = x + (size_t)rr * CIN;
                float4 va = (k0 < 100)
                    ? *(const float4*)(xr + k0) : make_float4(0.f, 0.f, 0.f, 0.f);
                float4 vb = (k0 + 4 < 100)
                    ? *(const float4*)(xr + k0 + 4) : make_float4(0.f, 0.f, 0.f, 0.f);
                ushort h0, h1, h2, h3, h4, h5, h6, h7;
                ushort l0, l1, l2, l3, l4, l5, l6, l7;
                bsplit(va.x, h0, l0); bsplit(va.y, h1, l1);
                bsplit(va.z, h2, l2); bsplit(va.w, h3, l3);
                bsplit(vb.x, h4, l4); bsplit(vb.y, h5, l5);
                bsplit(vb.z, h6, l6); bsplit(vb.w, h7, l7);
                v8s ah = {(short)h0, (short)h1, (short)h2, (short)h3,
                          (short)h4, (short)h5, (short)h6, (short)h7};
                v8s al = {(short)l0, (short)l1, (short)l2, (short)l3,
                          (short)l4, (short)l5, (short)l6, (short)l7};
                ahf[mt] = ah; alf[mt] = al;
            }
            int kgx = 128 + k0;                   // w1r section of w1T
            #pragma unroll
            for (int nt = 0; nt < 4; ++nt) {
                int n = chh * 64 + nt * 16 + l15;
                v8s bhf = *(const v8s*)(w1Th + (size_t)n * W1K + kgx);
                v8s blf = *(const v8s*)(w1Tl + (size_t)n * W1K + kgx);
                #pragma unroll
                for (int mt = 0; mt < 4; ++mt) {
                    acc[mt][nt] = __builtin_amdgcn_mfma_f32_16x16x32_bf16(
                        ahf[mt], bhf, acc[mt][nt], 0, 0, 0);
                    acc[mt][nt] = __builtin_amdgcn_mfma_f32_16x16x32_bf16(
                        alf[mt], bhf, acc[mt][nt], 0, 0, 0);
                    acc[mt][nt] = __builtin_amdgcn_mfma_f32_16x16x32_bf16(
                        ahf[mt], blf, acc[mt][nt], 0, 0, 0);
                }
            }
        }
        // C/D: col=l15, row=lg*4+r (verified layout). Write all 128 channels.
        #pragma unroll
        for (int nt = 0; nt < 4; ++nt) {
            int ch = chh * 64 + nt * 16 + l15;
            #pragma unroll
            for (int mt = 0; mt < 4; ++mt) {
                #pragma unroll
                for (int r = 0; r < 4; ++r) {
                    int node = base + nh * 64 + mt * 16 + lg * 4 + r;
                    if (node < N)
                        xw[(size_t)node * 128 + ch] = __float2half(acc[mt][nt][r]);
                }
            }
        }
        return;
    }
    // ---- gather block: one node per wave; two halves take even/odd edges,
    // unroll-4 per half; fp32 accumulation; cross-half __shfl_xor(..,32).
    int n = (blockIdx.x - XWB) * 4 + (t >> 6);
    int l = t & 63, half = l >> 5, li = l & 31;
    int b = row_ptr[n], e = row_ptr[n + 1];
    float inv = 1.0f / (float)max(e - b, 1);
    const uint2* xb = (const uint2*)x16;   // row = 25 uint2 (4 halves each)
    bool act = li < 25;
    float4 s0 = make_float4(0.f, 0.f, 0.f, 0.f);
    float4 s1 = make_float4(0.f, 0.f, 0.f, 0.f);
    float4 s2 = make_float4(0.f, 0.f, 0.f, 0.f);
    float4 s3 = make_float4(0.f, 0.f, 0.f, 0.f);
    union { uint2 u; __half2 h[2]; } U0, U1, U2, U3;
    int j = b + half;
    for (; j + 6 < e; j += 8) {
        int c0 = col[j], c1 = col[j + 2], c2 = col[j + 4], c3 = col[j + 6];
        if (act) {
            U0.u = xb[(size_t)c0 * 25 + li];
            U1.u = xb[(size_t)c1 * 25 + li];
            U2.u = xb[(size_t)c2 * 25 + li];
            U3.u = xb[(size_t)c3 * 25 + li];
            float2 f0a = __half22float2(U0.h[0]), f0b = __half22float2(U0.h[1]);
            float2 f1a = __half22float2(U1.h[0]), f1b = __half22float2(U1.h[1]);
            float2 f2a = __half22float2(U2.h[0]), f2b = __half22float2(U2.h[1]);
            float2 f3a = __half22float2(U3.h[0]), f3b = __half22float2(U3.h[1]);
            s0.x += f0a.x; s0.y += f0a.y; s0.z += f0b.x; s0.w += f0b.y;
            s1.x += f1a.x; s1.y += f1a.y; s1.z += f1b.x; s1.w += f1b.y;
            s2.x += f2a.x; s2.y += f2a.y; s2.z += f2b.x; s2.w += f2b.y;
            s3.x += f3a.x; s3.y += f3a.y; s3.z += f3b.x; s3.w += f3b.y;
        }
    }
    for (; j < e; j += 2) {
        int c0 = col[j];
        if (act) {
            U0.u = xb[(size_t)c0 * 25 + li];
            float2 f0a = __half22float2(U0.h[0]), f0b = __half22float2(U0.h[1]);
            s0.x += f0a.x; s0.y += f0a.y; s0.z += f0b.x; s0.w += f0b.y;
        }
    }
    float4 s = make_float4(s0.x + s1.x + s2.x + s3.x,
                           s0.y + s1.y + s2.y + s3.y,
                           s0.z + s1.z + s2.z + s3.z,
                           s0.w + s1.w + s2.w + s3.w);
    s.x += __shfl_xor(s.x, 32, 64);
    s.y += __shfl_xor(s.y, 32, 64);
    s.z += __shfl_xor(s.z, 32, 64);
    s.w += __shfl_xor(s.w, 32, 64);
    if (half == 0 && act) {
        __half2 p0 = __floats2half2_rn(s.x * inv, s.y * inv);
        __half2 p1 = __floats2half2_rn(s.z * inv, s.w * inv);
        union { __half2 h[2]; uint2 u; } P;
        P.h[0] = p0; P.h[1] = p1;
        ((uint2*)agg1h)[(size_t)n * 25 + li] = P.u;
    }
}

// ---------------------------------------------------------------------------
// fused gemm: split-bf16 MFMA. R18: stage 1 is only the agg1 half (K=128,
// 2 staged chunks; agg1 now fp16) + "acc += xw" (precomputed x@w1r).
// h round-trips LDS as bf16 hi/lo planes (stride 272B). 3-term hh+hl+lh.
// LDS = 69632 B -> 2 blocks/CU.
__global__ __launch_bounds__(256) void fused_gemm(
        const __half* __restrict__ agg1h, const __half* __restrict__ xw,
        const ushort* __restrict__ w1T, const float* __restrict__ b1l,
        const ushort* __restrict__ w2T, const float* __restrict__ b2cat,
        __half* __restrict__ gsrc16, float* __restrict__ gself) {
    __shared__ __align__(16) uint lds_u[17408];   // 69632 B
    ushort* Ah = (ushort*)lds_u;                  // [128][AS]  (stage-1 A hi)
    ushort* Al = Ah + 128 * AS;                   // [128][AS]  (stage-1 A lo)
    ushort* Hh = (ushort*)lds_u;                  // [128][HS]  (h hi; aliases)
    ushort* Hl = Hh + 128 * HS;                   // [128][HS]  (h lo)

    int t = threadIdx.x;
    int lane = t & 63;
    int wv = __builtin_amdgcn_readfirstlane(t >> 6);
    int nh = wv & 1, chh = wv >> 1;
    int l15 = lane & 15, lg = lane >> 4;
    int base = blockIdx.x * TN;

    const ushort* w1Th = w1T;
    const ushort* w1Tl = w1T + 128 * W1K;
    const ushort* w2Th = w2T;
    const ushort* w2Tl = w2T + 128 * W2K;

    f32x4 acc[4][4];
    #pragma unroll
    for (int nt = 0; nt < 4; ++nt) {
        float bv = b1l[chh * 64 + nt * 16 + l15];
        #pragma unroll
        for (int mt = 0; mt < 4; ++mt)
            acc[mt][nt] = f32x4{bv, bv, bv, bv};
    }

    int srow = t >> 1, sq = t & 1;                // staging: 2 threads/row
    int nmax = N - 1 - base; if (nmax > TN - 1) nmax = TN - 1;
    int srr = srow <= nmax ? srow : nmax;
    const uint2* Fp = (const uint2*)(agg1h + (size_t)(base + srr) * CIN);

    // prologue: chunk 0 (cols 0..15 u2, all valid)
    uint2 rv[8];
    #pragma unroll
    for (int q = 0; q < 8; ++q) rv[q] = Fp[sq * 8 + q];

    // ---- stage 1: 2 chunks of 64 k (agg1 only), 1-deep register prefetch
    for (int c = 0; c < 2; ++c) {
        uint2 nv[8];
        if (c == 0) {
            #pragma unroll
            for (int q = 0; q < 8; ++q) {
                int cj = 16 + sq * 8 + q;
                nv[q] = (cj < 25) ? Fp[cj] : make_uint2(0u, 0u);
            }
        }
        #pragma unroll
        for (int q = 0; q < 8; ++q) {             // unpack fp16 + bsplit + LDS
            union { uint2 u; __half2 h[2]; } V; V.u = rv[q];
            float2 fa = __half22float2(V.h[0]);
            float2 fb = __half22float2(V.h[1]);
            ushort h0, h1, h2, h3, l0, l1, l2, l3;
            bsplit(fa.x, h0, l0); bsplit(fa.y, h1, l1);
            bsplit(fb.x, h2, l2); bsplit(fb.y, h3, l3);
            int di = srow * AS + sq * 32 + q * 4;
            *(uint2*)(Ah + di) = make_uint2((uint)h0 | ((uint)h1 << 16),
                                            (uint)h2 | ((uint)h3 << 16));
            *(uint2*)(Al + di) = make_uint2((uint)l0 | ((uint)l1 << 16),
                                            (uint)l2 | ((uint)l3 << 16));
        }
        __syncthreads();
        #pragma unroll
        for (int ks = 0; ks < 2; ++ks) {          // 2 k-steps of 32 per chunk
            v8s ahf[4], alf[4];
            #pragma unroll
            for (int mt = 0; mt < 4; ++mt) {
                int row = nh * 64 + mt * 16 + l15;
                int ko = ks * 32 + lg * 8;
                ahf[mt] = *(const v8s*)(Ah + row * AS + ko);
                alf[mt] = *(const v8s*)(Al + row * AS + ko);
            }
            int kg = c * 64 + ks * 32 + lg * 8;   // w1l section (k<128)
            #pragma unroll
            for (int nt = 0; nt < 4; ++nt) {
                int n = chh * 64 + nt * 16 + l15;
                v8s bhf = *(const v8s*)(w1Th + (size_t)n * W1K + kg);
                v8s blf = *(const v8s*)(w1Tl + (size_t)n * W1K + kg);
                #pragma unroll
                for (int mt = 0; mt < 4; ++mt) {
                    acc[mt][nt] = __builtin_amdgcn_mfma_f32_16x16x32_bf16(
                        ahf[mt], bhf, acc[mt][nt], 0, 0, 0);
                    acc[mt][nt] = __builtin_amdgcn_mfma_f32_16x16x32_bf16(
                        alf[mt], bhf, acc[mt][nt], 0, 0, 0);
                    acc[mt][nt] = __builtin_amdgcn_mfma_f32_16x16x32_bf16(
                        ahf[mt], blf, acc[mt][nt], 0, 0, 0);
                }
            }
        }
        __syncthreads();
        if (c == 0) {
            #pragma unroll
            for (int q = 0; q < 8; ++q) rv[q] = nv[q];
        }
    }

    // ---- add precomputed x@w1r (xw, fp16)
    #pragma unroll
    for (int mt = 0; mt < 4; ++mt) {
        #pragma unroll
        for (int nt = 0; nt < 4; ++nt) {
            int ch = chh * 64 + nt * 16 + l15;
            #pragma unroll
            for (int r = 0; r < 4; ++r) {
                int node = base + nh * 64 + mt * 16 + lg * 4 + r;
                if (node < N)
                    acc[mt][nt][r] += __half2float(xw[(size_t)node * 128 + ch]);
            }
        }
    }

    // ---- spill h tile to LDS as bf16 hi/lo planes (aliases stage-1 bufs)
    #pragma unroll
    for (int mt = 0; mt < 4; ++mt) {
        #pragma unroll
        for (int nt = 0; nt < 4; ++nt) {
            int ch = chh * 64 + nt * 16 + l15;
            #pragma unroll
            for (int r = 0; r < 4; ++r) {
                int node = nh * 64 + mt * 16 + lg * 4 + r;
                ushort h, l; bsplit(acc[mt][nt][r], h, l);
                Hh[node * HS + ch] = h;
                Hl[node * HS + ch] = l;
            }
        }
    }
    __syncthreads();

    // ---- stage 2: [gsrc|gself] = h @ w2T^T (+ b2cat)
    bool skip = (chh == 1) && (base >= NOUT);
    if (!skip) {
        #pragma unroll
        for (int nt = 0; nt < 4; ++nt) {
            float bv = b2cat[chh * 64 + nt * 16 + l15];
            #pragma unroll
            for (int mt = 0; mt < 4; ++mt)
                acc[mt][nt] = f32x4{bv, bv, bv, bv};
        }
        #pragma unroll
        for (int ks = 0; ks < 4; ++ks) {          // K=128, 4 k-steps of 32
            v8s ahf[4], alf[4];
            #pragma unroll
            for (int mt = 0; mt < 4; ++mt) {
                int node = nh * 64 + mt * 16 + l15;
                int ko = ks * 32 + lg * 8;
                ahf[mt] = *(const v8s*)(Hh + node * HS + ko);
                alf[mt] = *(const v8s*)(Hl + node * HS + ko);
            }
            int kg = ks * 32 + lg * 8;
            #pragma unroll
            for (int nt = 0; nt < 4; ++nt) {
                int n = chh * 64 + nt * 16 + l15;
                v8s bhf = *(const v8s*)(w2Th + (size_t)n * W2K + kg);
                v8s blf = *(const v8s*)(w2Tl + (size_t)n * W2K + kg);
                #pragma unroll
                for (int mt = 0; mt < 4; ++mt) {
                    acc[mt][nt] = __builtin_amdgcn_mfma_f32_16x16x32_bf16(
                        ahf[mt], bhf, acc[mt][nt], 0, 0, 0);
                    acc[mt][nt] = __builtin_amdgcn_mfma_f32_16x16x32_bf16(
                        alf[mt], bhf, acc[mt][nt], 0, 0, 0);
                    acc[mt][nt] = __builtin_amdgcn_mfma_f32_16x16x32_bf16(
                        ahf[mt], blf, acc[mt][nt], 0, 0, 0);
                }
            }
        }
        int lim = chh ? NOUT : N;
        #pragma unroll
        for (int nt = 0; nt < 3; ++nt) {          // cols 0..47 only
            int colc = nt * 16 + l15;
            #pragma unroll
            for (int mt = 0; mt < 4; ++mt) {
                #pragma unroll
                for (int r = 0; r < 4; ++r) {
                    int node = base + nh * 64 + mt * 16 + lg * 4 + r;
                    if (node < lim) {
                        if (chh) gself[(size_t)node * CP + colc] = acc[mt][nt][r];
                        else gsrc16[(size_t)node * CP + colc] =
                                 __float2half(acc[mt][nt][r]);
                    }
                }
            }
        }
    }
}

// ---------------------------------------------------------------------------
// final: 4 nodes per 256-block (one per wave), unroll-4 fp16 gsrc gather.
// out nt store is safe: out is never read on-device.
__global__ __launch_bounds__(256) void final_kernel(const __half* __restrict__ gsrc16,
        const float* __restrict__ gself, const int* __restrict__ row_ptr,
        const int* __restrict__ col, float* __restrict__ out) {
    int t = threadIdx.x;
    int n = blockIdx.x * 4 + (t >> 6);
    int c = t & 63;
    int b = row_ptr[n], e = row_ptr[n + 1];
    float inv = 1.0f / (float)max(e - b, 1);
    float a0 = 0.f, a1 = 0.f, a2 = 0.f, a3 = 0.f;
    if (c < CP) {
        int j = b;
        for (; j + 3 < e; j += 4) {
            a0 += __half2float(gsrc16[(size_t)col[j]     * CP + c]);
            a1 += __half2float(gsrc16[(size_t)col[j + 1] * CP + c]);
            a2 += __half2float(gsrc16[(size_t)col[j + 2] * CP + c]);
            a3 += __half2float(gsrc16[(size_t)col[j + 3] * CP + c]);
        }
        for (; j < e; ++j) a0 += __half2float(gsrc16[(size_t)col[j] * CP + c]);
    }
    float val = (c < COUT)
        ? (((a0 + a1) + (a2 + a3)) * inv + gself[(size_t)n * CP + c]) : -INFINITY;
    float m = val;
    #pragma unroll
    for (int off = 32; off > 0; off >>= 1) m = fmaxf(m, __shfl_xor(m, off, 64));
    float ex = (c < COUT) ? expf(val - m) : 0.f;
    float ssum = ex;
    #pragma unroll
    for (int off = 32; off > 0; off >>= 1) ssum += __shfl_xor(ssum, off, 64);
    if (c < COUT)
        __builtin_nontemporal_store(val - m - logf(ssum),
                                    out + (size_t)n * COUT + c);
}

// ---------------------------------------------------------------------------
extern "C" void kernel_launch(void* const* d_in, const int* in_sizes, int n_in,
                              void* d_out, int out_size, void* d_ws, size_t ws_size,
                              hipStream_t stream) {
    const float* x   = (const float*)d_in[0];
    const int*   ei  = (const int*)d_in[1];   // [2, E]: row 0 = src, row 1 = dst
    const int*   src = ei;
    const int*   dst = ei + E;
    const float* w1l = (const float*)d_in[3];
    const float* b1l = (const float*)d_in[4];
    const float* w1r = (const float*)d_in[5];
    const float* w2l = (const float*)d_in[6];
    const float* b2l = (const float*)d_in[7];
    const float* w2r = (const float*)d_in[8];
    float* out = (float*)d_out;

    // ws: ints [cnt N | row_ptr N+1 | rank E | blkSum NB | col E]
    // floats [gself NOUT*CP | b2cat 128]
    // halves [gsrc16 N*CP | x16 N*CIN | agg1h N*CIN | xw N*128]
    // ushorts [w1T hi+lo 2*128*256 | w2T hi+lo 2*128*128]
    int* cnt     = (int*)d_ws;
    int* row_ptr = cnt + N;
    int* rank    = row_ptr + N + 1;
    int* blkSum  = rank + E;
    int* col     = blkSum + NB;
    size_t intWords = (size_t)N + (N + 1) + E + NB + E;
    intWords = (intWords + 3) & ~(size_t)3;
    float* gself  = (float*)d_ws + intWords;
    float* b2cat  = gself + (size_t)NOUT * CP;
    __half* gsrc16 = (__half*)(b2cat + 128);
    __half* x16    = gsrc16 + (size_t)N * CP;
    __half* agg1h  = x16 + (size_t)N * CIN;
    __half* xw     = agg1h + (size_t)N * CIN;
    ushort* w1T   = (ushort*)(xw + (size_t)N * 128);   // 16B-aligned
    ushort* w2T   = w1T + 2 * 128 * W1K;
    // total ws ~49.4 MB (< 58.6 MB proven available)

    (void)hipMemsetAsync(cnt, 0, (size_t)N * sizeof(int), stream);
    pre_kernel  <<<HB + CB + PB, 256, 0, stream>>>(dst, cnt, rank, x, x16,
                                                   w1l, w1r, w2l, w2r, b2l,
                                                   w1T, w2T, b2cat);
    scan_blocks <<<NB, 256, 0, stream>>>(cnt, row_ptr, blkSum);
    scan_apply  <<<NB, 256, 0, stream>>>(row_ptr, blkSum);
    fill_kernel <<<(E + 255) / 256, 256, 0, stream>>>(src, dst, rank, row_ptr, col);
    gather1_xw  <<<XWB + GB, 256, 0, stream>>>(x16, row_ptr, col, agg1h,
                                               x, w1T, xw);
    fused_gemm  <<<NT, 256, 0, stream>>>(agg1h, xw, w1T, b1l, w2T, b2cat,
                                         gsrc16, gself);
    final_kernel<<<NOUT / 4, 256, 0, stream>>>(gsrc16, gself, row_ptr, col, out);
}

// Round 9
// 227.181 us; speedup vs baseline: 1.3176x; 1.3176x over previous
//
#include <hip/hip_runtime.h>
#include <hip/hip_fp16.h>
#include <math.h>

// Problem constants (from reference setup_inputs)
constexpr int N    = 50000;   // nodes
constexpr int E    = 800000;  // edges
constexpr int CIN  = 100;     // input channels
constexpr int CH   = 128;     // hidden channels
constexpr int COUT = 47;      // output channels
constexpr int NOUT = 25000;   // original_size (rows emitted)
constexpr int CP   = 48;      // COUT padded (storage stride)
constexpr int NB   = (N + 255) / 256;        // 196 scan blocks
constexpr int TN   = 128;                    // gemm tile nodes
constexpr int NT   = (N + TN - 1) / TN;      // 391 gemm blocks

// MFMA split-bf16 constants
constexpr int HS  = 136;  // h LDS row stride (ushort) = 272 B (16B-aligned rows)
constexpr int W1K = 256;  // w1T row length (k): [agg1 0..99|0 | x 0..99|0]
constexpr int W2K = 128;  // w2T row length (k)
constexpr int A1S = 256;  // a1x row stride (halves) — mirrors w1T k-layout

// pre_kernel block partition
constexpr int HB = (E + 255) / 256;            // 3125 hist blocks
constexpr int CB = (N * 32) / 256;             // 6250 convert blocks (32 u2/row)
constexpr int PB = 193;                        // prep blocks (49280 elems)

typedef float f32x4 __attribute__((ext_vector_type(4)));
typedef short v8s  __attribute__((ext_vector_type(8)));   // 8 bf16 (4 VGPRs)

// split fp32 -> truncated bf16 hi + bf16(residual) lo. For fp16 inputs the
// split is EXACT (11-bit mantissa = 8 hi + <=3 lo); dropping lo*lo in the
// 3-term MFMA leaves ~2^-16 rel error per product.
__device__ __forceinline__ void bsplit(float f, ushort& h, ushort& l) {
    uint u = __float_as_uint(f);
    h = (ushort)(u >> 16);
    float fh = __uint_as_float(u & 0xffff0000u);
    l = (ushort)(__float_as_uint(f - fh) >> 16);
}

// unpack 8 fp16 (one 16B vector) -> bf16 hi/lo MFMA fragments
__device__ __forceinline__ void unpack8(uint4 v, v8s& ah, v8s& al) {
    union { uint4 u; __half2 h[4]; } V; V.u = v;
    ushort hh[8], ll[8];
    #pragma unroll
    for (int p = 0; p < 4; ++p) {
        float2 f = __half22float2(V.h[p]);
        bsplit(f.x, hh[2 * p],     ll[2 * p]);
        bsplit(f.y, hh[2 * p + 1], ll[2 * p + 1]);
    }
    ah = v8s{(short)hh[0], (short)hh[1], (short)hh[2], (short)hh[3],
             (short)hh[4], (short)hh[5], (short)hh[6], (short)hh[7]};
    al = v8s{(short)ll[0], (short)ll[1], (short)ll[2], (short)ll[3],
             (short)ll[4], (short)ll[5], (short)ll[6], (short)ll[7]};
}

// ---------------------------------------------------------------------------
// pre_kernel: fused {hist | convert_x | prep_w} — all low-VGPR branches only
// (R18 lesson: never fuse a fat-register branch into latency-bound work).
__global__ __launch_bounds__(256) void pre_kernel(
        const int* __restrict__ dst, int* __restrict__ cnt, int* __restrict__ rank,
        const float* __restrict__ x, __half* __restrict__ x16,
        __half* __restrict__ a1x,
        const float* __restrict__ w1l, const float* __restrict__ w1r,
        const float* __restrict__ w2l, const float* __restrict__ w2r,
        const float* __restrict__ b2l,
        ushort* __restrict__ w1T, ushort* __restrict__ w2T,
        float* __restrict__ b2cat) {
    int bid = blockIdx.x, t = threadIdx.x;
    if (bid < HB) {
        // in-degree histogram; rank[i] = slot of edge i within its dst bucket
        int i = bid * 256 + t;
        if (i < E) rank[i] = atomicAdd(&cnt[dst[i]], 1);
    } else if (bid < HB + CB) {
        // x -> fp16: packed x16[N][100] (gather payload) AND the x-section of
        // a1x[N][256] halves 128..255 (cols >=100 zeroed).
        int j = (bid - HB) * 256 + t;      // j over N*32 u2 slots
        int row = j >> 5, s = j & 31;
        uint2 u = make_uint2(0u, 0u);
        if (s < 25) {
            float4 v = ((const float4*)x)[row * 25 + s];
            __half2 h0 = __floats2half2_rn(v.x, v.y);
            __half2 h1 = __floats2half2_rn(v.z, v.w);
            union { __half2 h[2]; uint2 u; } U;
            U.h[0] = h0; U.h[1] = h1;
            u = U.u;
            ((uint2*)x16)[row * 25 + s] = u;
        }
        ((uint2*)a1x)[(size_t)row * 64 + 32 + s] = u;
    } else {
        // weight transpose + bf16 hi/lo split
        // w1T: [n<128][k<256]: k<100 -> w1l[k][n]; 128<=k<228 -> w1r[k-128][n]
        // w2T: [n<128][k<128]: n<47 -> w2l[k][n]; 64<=n<111 -> w2r[k][n-64]
        int i = (bid - HB - CB) * 256 + t;
        if (i < 128 * W1K) {
            int n = i >> 8, k = i & 255;
            float v = 0.0f;
            if (k < 100)                    v = w1l[(size_t)k * CH + n];
            else if (k >= 128 && k < 228)   v = w1r[(size_t)(k - 128) * CH + n];
            ushort h, l; bsplit(v, h, l);
            w1T[i] = h; w1T[128 * W1K + i] = l;
        } else if (i < 128 * W1K + 128 * W2K) {
            int j2 = i - 128 * W1K;
            int n = j2 >> 7, k = j2 & 127;
            float v = 0.0f;
            if (n < COUT)                      v = w2l[(size_t)k * COUT + n];
            else if (n >= 64 && n < 64 + COUT) v = w2r[(size_t)k * COUT + (n - 64)];
            ushort h, l; bsplit(v, h, l);
            w2T[j2] = h; w2T[128 * W2K + j2] = l;
        } else {
            int j2 = i - (128 * W1K + 128 * W2K);
            if (j2 < 128) b2cat[j2] = (j2 >= 64 && j2 < 64 + COUT) ? b2l[j2 - 64] : 0.0f;
        }
    }
}

// CSR stage 2a: per-block exclusive scan of cnt
__global__ __launch_bounds__(256) void scan_blocks(const int* __restrict__ cnt,
        int* __restrict__ row_ptr, int* __restrict__ blkSum) {
    __shared__ int s[256];
    int t = threadIdx.x;
    int i = blockIdx.x * 256 + t;
    int v = (i < N) ? cnt[i] : 0;
    s[t] = v;
    __syncthreads();
    for (int off = 1; off < 256; off <<= 1) {
        int a = s[t];
        int u = (t >= off) ? s[t - off] : 0;
        __syncthreads();
        s[t] = a + u;
        __syncthreads();
    }
    if (i < N) row_ptr[i] = s[t] - v;
    if (t == 255) blkSum[blockIdx.x] = s[255];
}

// CSR stage 2b: each block reduces blkSum[0..bid) itself, applies offset.
__global__ __launch_bounds__(256) void scan_apply(int* __restrict__ row_ptr,
        const int* __restrict__ blkSum) {
    __shared__ int s[256];
    int t = threadIdx.x, bid = blockIdx.x;
    int a = 0;
    for (int j = t; j < bid; j += 256) a += blkSum[j];
    s[t] = a;
    __syncthreads();
    for (int off = 128; off > 0; off >>= 1) {
        if (t < off) s[t] += s[t + off];
        __syncthreads();
    }
    int offset = s[0];
    int i = bid * 256 + t;
    if (i < N) {
        row_ptr[i] += offset;
        if (i == N - 1) row_ptr[N] = E;
    }
}

// CSR stage 3: atomic-free bucket-fill (plain stores — R16 lesson).
__global__ void fill_kernel(const int* __restrict__ src, const int* __restrict__ dst,
        const int* __restrict__ rank, const int* __restrict__ row_ptr,
        int* __restrict__ col) {
    int i = blockIdx.x * blockDim.x + threadIdx.x;
    if (i < E) col[row_ptr[dst[i]] + rank[i]] = src[i];
}

// ---------------------------------------------------------------------------
// gather1 (standalone again — 24 VGPR, high occupancy; R18 lesson): fp16
// source rows (200B). One node per wave; two 32-lane halves take even/odd
// edges, unroll-4 per half; fp32 accumulation; cross-half __shfl_xor(..,32).
// Output: agg-section of a1x (halves 0..127; li>=25 lanes write the zero pad).
__global__ __launch_bounds__(256) void gather1_kernel(const __half* __restrict__ x16,
        const int* __restrict__ row_ptr, const int* __restrict__ col,
        __half* __restrict__ a1x) {
    int t = threadIdx.x;
    int n = blockIdx.x * 4 + (t >> 6);     // node per wave
    int l = t & 63, half = l >> 5, li = l & 31;
    int b = row_ptr[n], e = row_ptr[n + 1];
    float inv = 1.0f / (float)max(e - b, 1);
    const uint2* xb = (const uint2*)x16;   // row = 25 uint2 (4 halves each)
    bool act = li < 25;
    float4 s0 = make_float4(0.f, 0.f, 0.f, 0.f);
    float4 s1 = make_float4(0.f, 0.f, 0.f, 0.f);
    float4 s2 = make_float4(0.f, 0.f, 0.f, 0.f);
    float4 s3 = make_float4(0.f, 0.f, 0.f, 0.f);
    union { uint2 u; __half2 h[2]; } U0, U1, U2, U3;
    int j = b + half;
    for (; j + 6 < e; j += 8) {
        int c0 = col[j], c1 = col[j + 2], c2 = col[j + 4], c3 = col[j + 6];
        if (act) {
            U0.u = xb[(size_t)c0 * 25 + li];
            U1.u = xb[(size_t)c1 * 25 + li];
            U2.u = xb[(size_t)c2 * 25 + li];
            U3.u = xb[(size_t)c3 * 25 + li];
            float2 f0a = __half22float2(U0.h[0]), f0b = __half22float2(U0.h[1]);
            float2 f1a = __half22float2(U1.h[0]), f1b = __half22float2(U1.h[1]);
            float2 f2a = __half22float2(U2.h[0]), f2b = __half22float2(U2.h[1]);
            float2 f3a = __half22float2(U3.h[0]), f3b = __half22float2(U3.h[1]);
            s0.x += f0a.x; s0.y += f0a.y; s0.z += f0b.x; s0.w += f0b.y;
            s1.x += f1a.x; s1.y += f1a.y; s1.z += f1b.x; s1.w += f1b.y;
            s2.x += f2a.x; s2.y += f2a.y; s2.z += f2b.x; s2.w += f2b.y;
            s3.x += f3a.x; s3.y += f3a.y; s3.z += f3b.x; s3.w += f3b.y;
        }
    }
    for (; j < e; j += 2) {
        int c0 = col[j];
        if (act) {
            U0.u = xb[(size_t)c0 * 25 + li];
            float2 f0a = __half22float2(U0.h[0]), f0b = __half22float2(U0.h[1]);
            s0.x += f0a.x; s0.y += f0a.y; s0.z += f0b.x; s0.w += f0b.y;
        }
    }
    float4 s = make_float4(s0.x + s1.x + s2.x + s3.x,
                           s0.y + s1.y + s2.y + s3.y,
                           s0.z + s1.z + s2.z + s3.z,
                           s0.w + s1.w + s2.w + s3.w);
    s.x += __shfl_xor(s.x, 32, 64);
    s.y += __shfl_xor(s.y, 32, 64);
    s.z += __shfl_xor(s.z, 32, 64);
    s.w += __shfl_xor(s.w, 32, 64);
    if (half == 0) {                      // li>=25 lanes hold zeros -> pad
        __half2 p0 = __floats2half2_rn(s.x * inv, s.y * inv);
        __half2 p1 = __floats2half2_rn(s.z * inv, s.w * inv);
        union { __half2 h[2]; uint2 u; } P;
        P.h[0] = p0; P.h[1] = p1;
        ((uint2*)a1x)[(size_t)n * 64 + li] = P.u;
    }
}

// ---------------------------------------------------------------------------
// R19 fused gemm: stage-1 is a single K=256 LDS-FREE direct-load GEMM —
// A-frags (16B = 8 fp16) read straight from a1x[N][256] (= [agg1|0|x|0],
// mirroring w1T's k-layout), bsplit in-register. No staging, no stage-1
// barriers. h spills to LDS as bf16 hi/lo planes (stride 272B, ONE barrier),
// then stage-2 = h @ w2T^T. 3-term hh+hl+lh in fp32.
// LDS = 69632 B (H planes only) -> 2 blocks/CU.
__global__ __launch_bounds__(256) void fused_gemm(
        const __half* __restrict__ a1x,
        const ushort* __restrict__ w1T, const float* __restrict__ b1l,
        const ushort* __restrict__ w2T, const float* __restrict__ b2cat,
        __half* __restrict__ gsrc16, float* __restrict__ gself) {
    __shared__ __align__(16) uint lds_u[17408];   // 69632 B
    ushort* Hh = (ushort*)lds_u;                  // [128][HS]  (h hi)
    ushort* Hl = Hh + 128 * HS;                   // [128][HS]  (h lo)

    int t = threadIdx.x;
    int lane = t & 63;
    int wv = __builtin_amdgcn_readfirstlane(t >> 6);
    int nh = wv & 1, chh = wv >> 1;
    int l15 = lane & 15, lg = lane >> 4;
    int base = blockIdx.x * TN;

    const ushort* w1Th = w1T;
    const ushort* w1Tl = w1T + 128 * W1K;
    const ushort* w2Th = w2T;
    const ushort* w2Tl = w2T + 128 * W2K;

    f32x4 acc[4][4];
    #pragma unroll
    for (int nt = 0; nt < 4; ++nt) {
        float bv = b1l[chh * 64 + nt * 16 + l15];
        #pragma unroll
        for (int mt = 0; mt < 4; ++mt)
            acc[mt][nt] = f32x4{bv, bv, bv, bv};
    }

    // ---- stage 1: K=256, direct loads, no LDS, no barriers
    #pragma unroll 2
    for (int ks = 0; ks < 8; ++ks) {
        int k0 = ks * 32 + lg * 8;
        v8s ahf[4], alf[4];
        #pragma unroll
        for (int mt = 0; mt < 4; ++mt) {
            int row = base + nh * 64 + mt * 16 + l15;
            int rr = row < N ? row : N - 1;       // clamp loads; stores guarded
            uint4 v = *(const uint4*)(a1x + (size_t)rr * A1S + k0);
            unpack8(v, ahf[mt], alf[mt]);
        }
        #pragma unroll
        for (int nt = 0; nt < 4; ++nt) {
            int n = chh * 64 + nt * 16 + l15;
            v8s bhf = *(const v8s*)(w1Th + (size_t)n * W1K + k0);
            v8s blf = *(const v8s*)(w1Tl + (size_t)n * W1K + k0);
            #pragma unroll
            for (int mt = 0; mt < 4; ++mt) {
                acc[mt][nt] = __builtin_amdgcn_mfma_f32_16x16x32_bf16(
                    ahf[mt], bhf, acc[mt][nt], 0, 0, 0);
                acc[mt][nt] = __builtin_amdgcn_mfma_f32_16x16x32_bf16(
                    alf[mt], bhf, acc[mt][nt], 0, 0, 0);
                acc[mt][nt] = __builtin_amdgcn_mfma_f32_16x16x32_bf16(
                    ahf[mt], blf, acc[mt][nt], 0, 0, 0);
            }
        }
    }

    // ---- spill h tile to LDS as bf16 hi/lo planes
    #pragma unroll
    for (int mt = 0; mt < 4; ++mt) {
        #pragma unroll
        for (int nt = 0; nt < 4; ++nt) {
            int ch = chh * 64 + nt * 16 + l15;
            #pragma unroll
            for (int r = 0; r < 4; ++r) {
                int node = nh * 64 + mt * 16 + lg * 4 + r;
                ushort h, l; bsplit(acc[mt][nt][r], h, l);
                Hh[node * HS + ch] = h;
                Hl[node * HS + ch] = l;
            }
        }
    }
    __syncthreads();

    // ---- stage 2: [gsrc|gself] = h @ w2T^T (+ b2cat)
    bool skip = (chh == 1) && (base >= NOUT);
    if (!skip) {
        #pragma unroll
        for (int nt = 0; nt < 4; ++nt) {
            float bv = b2cat[chh * 64 + nt * 16 + l15];
            #pragma unroll
            for (int mt = 0; mt < 4; ++mt)
                acc[mt][nt] = f32x4{bv, bv, bv, bv};
        }
        #pragma unroll
        for (int ks = 0; ks < 4; ++ks) {          // K=128, 4 k-steps of 32
            v8s ahf[4], alf[4];
            #pragma unroll
            for (int mt = 0; mt < 4; ++mt) {
                int node = nh * 64 + mt * 16 + l15;
                int ko = ks * 32 + lg * 8;
                ahf[mt] = *(const v8s*)(Hh + node * HS + ko);
                alf[mt] = *(const v8s*)(Hl + node * HS + ko);
            }
            int kg = ks * 32 + lg * 8;
            #pragma unroll
            for (int nt = 0; nt < 4; ++nt) {
                int n = chh * 64 + nt * 16 + l15;
                v8s bhf = *(const v8s*)(w2Th + (size_t)n * W2K + kg);
                v8s blf = *(const v8s*)(w2Tl + (size_t)n * W2K + kg);
                #pragma unroll
                for (int mt = 0; mt < 4; ++mt) {
                    acc[mt][nt] = __builtin_amdgcn_mfma_f32_16x16x32_bf16(
                        ahf[mt], bhf, acc[mt][nt], 0, 0, 0);
                    acc[mt][nt] = __builtin_amdgcn_mfma_f32_16x16x32_bf16(
                        alf[mt], bhf, acc[mt][nt], 0, 0, 0);
                    acc[mt][nt] = __builtin_amdgcn_mfma_f32_16x16x32_bf16(
                        ahf[mt], blf, acc[mt][nt], 0, 0, 0);
                }
            }
        }
        int lim = chh ? NOUT : N;
        #pragma unroll
        for (int nt = 0; nt < 3; ++nt) {          // cols 0..47 only
            int colc = nt * 16 + l15;
            #pragma unroll
            for (int mt = 0; mt < 4; ++mt) {
                #pragma unroll
                for (int r = 0; r < 4; ++r) {
                    int node = base + nh * 64 + mt * 16 + lg * 4 + r;
                    if (node < lim) {
                        if (chh) gself[(size_t)node * CP + colc] = acc[mt][nt][r];
                        else gsrc16[(size_t)node * CP + colc] =
                                 __float2half(acc[mt][nt][r]);
                    }
                }
            }
        }
    }
}

// ---------------------------------------------------------------------------
// final: 4 nodes per 256-block (one per wave), unroll-4 fp16 gsrc gather.
// out nt store is safe: out is never read on-device.
__global__ __launch_bounds__(256) void final_kernel(const __half* __restrict__ gsrc16,
        const float* __restrict__ gself, const int* __restrict__ row_ptr,
        const int* __restrict__ col, float* __restrict__ out) {
    int t = threadIdx.x;
    int n = blockIdx.x * 4 + (t >> 6);
    int c = t & 63;
    int b = row_ptr[n], e = row_ptr[n + 1];
    float inv = 1.0f / (float)max(e - b, 1);
    float a0 = 0.f, a1 = 0.f, a2 = 0.f, a3 = 0.f;
    if (c < CP) {
        int j = b;
        for (; j + 3 < e; j += 4) {
            a0 += __half2float(gsrc16[(size_t)col[j]     * CP + c]);
            a1 += __half2float(gsrc16[(size_t)col[j + 1] * CP + c]);
            a2 += __half2float(gsrc16[(size_t)col[j + 2] * CP + c]);
            a3 += __half2float(gsrc16[(size_t)col[j + 3] * CP + c]);
        }
        for (; j < e; ++j) a0 += __half2float(gsrc16[(size_t)col[j] * CP + c]);
    }
    float val = (c < COUT)
        ? (((a0 + a1) + (a2 + a3)) * inv + gself[(size_t)n * CP + c]) : -INFINITY;
    float m = val;
    #pragma unroll
    for (int off = 32; off > 0; off >>= 1) m = fmaxf(m, __shfl_xor(m, off, 64));
    float ex = (c < COUT) ? expf(val - m) : 0.f;
    float ssum = ex;
    #pragma unroll
    for (int off = 32; off > 0; off >>= 1) ssum += __shfl_xor(ssum, off, 64);
    if (c < COUT)
        __builtin_nontemporal_store(val - m - logf(ssum),
                                    out + (size_t)n * COUT + c);
}

// ---------------------------------------------------------------------------
extern "C" void kernel_launch(void* const* d_in, const int* in_sizes, int n_in,
                              void* d_out, int out_size, void* d_ws, size_t ws_size,
                              hipStream_t stream) {
    const float* x   = (const float*)d_in[0];
    const int*   ei  = (const int*)d_in[1];   // [2, E]: row 0 = src, row 1 = dst
    const int*   src = ei;
    const int*   dst = ei + E;
    const float* w1l = (const float*)d_in[3];
    const float* b1l = (const float*)d_in[4];
    const float* w1r = (const float*)d_in[5];
    const float* w2l = (const float*)d_in[6];
    const float* b2l = (const float*)d_in[7];
    const float* w2r = (const float*)d_in[8];
    float* out = (float*)d_out;

    // ws: ints [cnt N | row_ptr N+1 | rank E | blkSum NB | col E]
    // floats [gself NOUT*CP | b2cat 128]
    // halves [gsrc16 N*CP | x16 N*CIN | a1x N*256]
    // ushorts [w1T hi+lo 2*128*256 | w2T hi+lo 2*128*128]
    int* cnt     = (int*)d_ws;
    int* row_ptr = cnt + N;
    int* rank    = row_ptr + N + 1;
    int* blkSum  = rank + E;
    int* col     = blkSum + NB;
    size_t intWords = (size_t)N + (N + 1) + E + NB + E;
    intWords = (intWords + 3) & ~(size_t)3;
    float* gself  = (float*)d_ws + intWords;
    float* b2cat  = gself + (size_t)NOUT * CP;
    __half* gsrc16 = (__half*)(b2cat + 128);
    __half* x16    = gsrc16 + (size_t)N * CP;
    __half* a1x    = x16 + (size_t)N * CIN;       // 16B-aligned (counts %8==0)
    ushort* w1T   = (ushort*)(a1x + (size_t)N * A1S);
    ushort* w2T   = w1T + 2 * 128 * W1K;
    // total ws ~52.4 MB (< 58.6 MB proven available)

    (void)hipMemsetAsync(cnt, 0, (size_t)N * sizeof(int), stream);
    pre_kernel  <<<HB + CB + PB, 256, 0, stream>>>(dst, cnt, rank, x, x16, a1x,
                                                   w1l, w1r, w2l, w2r, b2l,
                                                   w1T, w2T, b2cat);
    scan_blocks <<<NB, 256, 0, stream>>>(cnt, row_ptr, blkSum);
    scan_apply  <<<NB, 256, 0, stream>>>(row_ptr, blkSum);
    fill_kernel <<<(E + 255) / 256, 256, 0, stream>>>(src, dst, rank, row_ptr, col);
    gather1_kernel<<<N / 4, 256, 0, stream>>>(x16, row_ptr, col, a1x);
    fused_gemm  <<<NT, 256, 0, stream>>>(a1x, w1T, b1l, w2T, b2cat,
                                         gsrc16, gself);
    final_kernel<<<NOUT / 4, 256, 0, stream>>>(gsrc16, gself, row_ptr, col, out);
}